// Round 11
// baseline (206.679 us; speedup 1.0000x reference)
//
#include <hip/hip_runtime.h>

// Permutohedral lattice filter, PD=3, VD=5 (4 channels + homogeneous 1)
// Dense-grid lattice addressing: keys (k0,k1,k2) all share residue mod 4 and
// (for the fixed feature scales coords/5) fit K0=k0+16, K1=k1+48, K2=k2+88,
// each in [0,128). Dense index = (K2>>2,K1>>2,K0>>2,K0&3) -> 2^17 cells.
//
// Splat: per-block DIRECT-MAPPED LDS box (no hash, no CAS) + register
// run-merging along x + lane-spread thread->x mapping. Blur: single
// persistent kernel (64 blocks) with atomic grid barriers between the 4
// passes. Slice: separate full-occupancy dispatch.

#define DD    64
#define HHH   128
#define WWW   128
#define NPTS  (DD * HHH * WWW)          // 1048576
#define LATN  (1 << 17)                 // dense lattice cells
#define LATF  (LATN * 5)                // floats per lattice buffer
#define DQ    7                         // box quads per axis
#define CELLS (DQ * DQ * DQ * 4)        // 1372
#define MASKW ((CELLS + 31) / 32)       // 43
#define BLURG 64                        // fused-blur grid

__device__ __forceinline__ int encK(int K0, int K1, int K2) {
    return ((K2 >> 2) << 12) | ((K1 >> 2) << 7) | ((K0 >> 2) << 2) | (K0 & 3);
}

// Full per-point geometry: elevate, round, rank, barycentric. Outputs the 4
// corner keys in offset K-space (K0=k0+16, K1=k1+48, K2=k2+88) and weights.
__device__ __forceinline__ void pl_geom(int z, int y, int x,
                                        const float* __restrict__ vg,
                                        const float* __restrict__ sg,
                                        int* Kout /*[4*3]*/, float* bout) {
    // features = [zz, yy, xx]; v_gamma[1] pairs with x, v_gamma[2] with y
    float f0 = vg[0] * (float)z / sg[0];
    float f1 = vg[2] * (float)y / sg[2];
    float f2 = vg[1] * (float)x / sg[1];

    const float m00 = (float)2.3094010767585034;   //  4/sqrt(3)
    const float m01 = (float)1.3333333333333333;   //  4/3
    const float m02 = (float)0.9428090415820634;   //  2*sqrt(2)/3
    const float m21 = (float)-2.6666666666666665;  // -2*(4/3)
    const float m32 = (float)-2.8284271247461903;  // -3*(2*sqrt(2)/3)

    float e[4];
    e[0] =  m00 * f0 + m01 * f1 + m02 * f2;
    e[1] = -m00 * f0 + m01 * f1 + m02 * f2;
    e[2] =  m21 * f1 + m02 * f2;
    e[3] =  m32 * f2;

    float rem0[4];
    int sumr = 0;
    #pragma unroll
    for (int i = 0; i < 4; ++i) {
        float v = e[i] * 0.25f;
        float up = ceilf(v), dn = floorf(v);
        float rr = ((up - v) < (v - dn)) ? up : dn;
        rem0[i] = rr * 4.0f;
        sumr += (int)rem0[i];
    }
    sumr /= 4;   // exact: sum of multiples of 4

    float diff[4];
    #pragma unroll
    for (int i = 0; i < 4; ++i) diff[i] = e[i] - rem0[i];
    int rank[4] = {0, 0, 0, 0};
    #pragma unroll
    for (int i = 0; i < 4; ++i)
        #pragma unroll
        for (int j = i + 1; j < 4; ++j) {
            if (diff[i] < diff[j]) rank[i]++; else rank[j]++;
        }

    #pragma unroll
    for (int i = 0; i < 4; ++i) {
        rank[i] += sumr;
        if (rank[i] < 0)      { rank[i] += 4; rem0[i] += 4.0f; }
        else if (rank[i] > 3) { rank[i] -= 4; rem0[i] -= 4.0f; }
    }

    float b[5] = {0.f, 0.f, 0.f, 0.f, 0.f};
    #pragma unroll
    for (int i = 0; i < 4; ++i) {
        float t = (e[i] - rem0[i]) * 0.25f;
        b[3 - rank[i]] += t;
        b[4 - rank[i]] -= t;
    }
    b[0] += 1.0f + b[4];

    int k0 = (int)rem0[0] + 16, k1 = (int)rem0[1] + 48, k2 = (int)rem0[2] + 88;
    #pragma unroll
    for (int r = 0; r < 4; ++r) {
        int o0 = (rank[0] >= 4 - r) ? (r - 4) : r;
        int o1 = (rank[1] >= 4 - r) ? (r - 4) : r;
        int o2 = (rank[2] >= 4 - r) ? (r - 4) : r;
        Kout[r * 3 + 0] = k0 + o0;
        Kout[r * 3 + 1] = k1 + o1;
        Kout[r * 3 + 2] = k2 + o2;
        bout[r] = b[r];
    }
}

// ---------------------------------------------------------------- splat
__device__ __forceinline__ void pl_claim(int key, unsigned int* __restrict__ exists,
                                         int* __restrict__ wcnt, int* __restrict__ wl) {
    if (atomicExch(&exists[key], 1u) == 0u) {
        int p = atomicAdd(wcnt, 1);
        wl[p] = key;
    }
}

// id >= 0 : box cell index.  id < 0 : ~id = dense lattice key (escape).
__device__ __forceinline__ int make_id(const int* K, int B0, int B1, int B2) {
    int l0 = K[0] - B0, l1 = K[1] - B1, l2 = K[2] - B2;
    if (((unsigned)l0 < 4u * DQ) & ((unsigned)l1 < 4u * DQ) & ((unsigned)l2 < 4u * DQ))
        return ((((l2 >> 2) * DQ) + (l1 >> 2)) * DQ + (l0 >> 2)) * 4 + (l0 & 3);
    return ~encK(K[0] & 127, K[1] & 127, K[2] & 127);
}

__device__ __forceinline__ void pl_emit(int id, const float* a,
                                        float* sacc, unsigned int* smask,
                                        float* __restrict__ mycopy,
                                        unsigned int* __restrict__ exists,
                                        int* __restrict__ wcnt, int* __restrict__ wl) {
    if (id >= 0) {
        #pragma unroll
        for (int c = 0; c < 5; ++c) atomicAdd(&sacc[id * 5 + c], a[c]);
        atomicOr(&smask[id >> 5], 1u << (id & 31));
    } else {                              // out-of-box escape (rare)
        int key = ~id;
        float* L = mycopy + (size_t)key * 5;
        #pragma unroll
        for (int c = 0; c < 5; ++c) atomicAdd(L + c, a[c]);
        pl_claim(key, exists, wcnt, wl);
    }
}

// Block = 512 threads covering a 32x8x8 (x,y,z) tile, 4 consecutive x px per
// thread with register run-merging; thread->x slot spread so adjacent lanes
// are 8 px apart. Box span check (s=1/5): e0 = .462*7+.267*7+.189*31 = 10.95,
// +13 window +3 align = 26.95 <= 28 OK; e2 = .533*7+.189*31 = 9.58, +16 =
// 25.6 <= 28 OK. Flush scans the box, global-atomics into latc[blockIdx&3].
__global__ __launch_bounds__(512, 4)
void pl_splat(const float* __restrict__ vals, const float* __restrict__ vg,
              const float* __restrict__ sg, float* __restrict__ latc,
              unsigned int* __restrict__ exists,
              int* __restrict__ wcnt, int* __restrict__ wl) {
    __shared__ float4 sacc4[CELLS * 5 / 4];   // 6860 floats = 27440 B
    __shared__ unsigned int smask[MASKW];     // 172 B
    float* sacc = (float*)sacc4;
    for (int i = threadIdx.x; i < CELLS * 5 / 4; i += 512)
        sacc4[i] = make_float4(0.f, 0.f, 0.f, 0.f);
    if (threadIdx.x < MASKW) smask[threadIdx.x] = 0u;
    __syncthreads();

    // tile decode: grid = 4(x) * 16(y) * 8(z) = 512 blocks
    int bt = blockIdx.x;
    int tx = (bt & 3) << 5;
    int ty = ((bt >> 2) & 15) << 3;
    int tz = (bt >> 6) << 3;

    // per-block box base (uniform): analytic min corner of the key range.
    // K - e in [-7, 6]  =>  base = floor(emin + OFF - 7) & ~3.
    float s0 = vg[0] / sg[0], s1 = vg[2] / sg[2], s2 = vg[1] / sg[1];
    const float m00 = 2.30940104f, m01 = 1.33333325f, m02 = 0.942809045f,
                m21 = -2.66666651f;
    float A0z = m00 * s0, A0y = m01 * s1, A0x = m02 * s2;
    float A1z = -A0z,     A1y = A0y,      A1x = A0x;
    float A2y = m21 * s1, A2x = A0x;
    float e0o = A0z * tz + A0y * ty + A0x * tx;
    float e1o = A1z * tz + A1y * ty + A1x * tx;
    float e2o = A2y * ty + A2x * tx;
    float e0m = e0o + fminf(0.f, A0z) * 7 + fminf(0.f, A0y) * 7 + fminf(0.f, A0x) * 31;
    float e1m = e1o + fminf(0.f, A1z) * 7 + fminf(0.f, A1y) * 7 + fminf(0.f, A1x) * 31;
    float e2m = e2o + fminf(0.f, A2y) * 7 + fminf(0.f, A2x) * 31;
    int B0 = ((int)floorf(e0m + 16.f - 7.f)) & ~3;
    int B1 = ((int)floorf(e1m + 48.f - 7.f)) & ~3;
    int B2 = ((int)floorf(e2m + 88.f - 7.f)) & ~3;

    // thread -> x slot, spread so adjacent lanes are 8 px apart
    int xs = threadIdx.x & 7;
    int xsl = ((xs & 3) << 1) | (xs >> 2);   // 0,2,4,6,1,3,5,7
    int x0 = tx + (xsl << 2);
    int y  = ty + ((threadIdx.x >> 3) & 7);
    int z  = tz + (threadIdx.x >> 6);
    int n0 = (z << 14) + (y << 7) + x0;

    float4 q0 = *(const float4*)(vals + n0);
    float4 q1 = *(const float4*)(vals + NPTS + n0);
    float4 q2 = *(const float4*)(vals + 2 * NPTS + n0);
    float4 q3 = *(const float4*)(vals + 3 * NPTS + n0);
    float ch0[4] = {q0.x, q0.y, q0.z, q0.w};
    float ch1[4] = {q1.x, q1.y, q1.z, q1.w};
    float ch2[4] = {q2.x, q2.y, q2.z, q2.w};
    float ch3[4] = {q3.x, q3.y, q3.z, q3.w};

    float* mycopy = latc + (size_t)(blockIdx.x & 3) * LATF;

    int cid[4];
    float acc[4][5];
    {
        int K[12]; float b[4];
        pl_geom(z, y, x0, vg, sg, K, b);
        #pragma unroll
        for (int r = 0; r < 4; ++r) {
            cid[r] = make_id(K + r * 3, B0, B1, B2);
            float w = b[r];
            acc[r][0] = w * ch0[0]; acc[r][1] = w * ch1[0];
            acc[r][2] = w * ch2[0]; acc[r][3] = w * ch3[0];
            acc[r][4] = w;
        }
    }
    #pragma unroll
    for (int p = 1; p < 4; ++p) {
        int K[12]; float b[4];
        pl_geom(z, y, x0 + p, vg, sg, K, b);
        #pragma unroll
        for (int r = 0; r < 4; ++r) {
            int id = make_id(K + r * 3, B0, B1, B2);
            float w = b[r];
            if (id == cid[r]) {   // register run-merge (hit rate ~85%)
                acc[r][0] += w * ch0[p]; acc[r][1] += w * ch1[p];
                acc[r][2] += w * ch2[p]; acc[r][3] += w * ch3[p];
                acc[r][4] += w;
            } else {
                pl_emit(cid[r], acc[r], sacc, smask, mycopy, exists, wcnt, wl);
                cid[r] = id;
                acc[r][0] = w * ch0[p]; acc[r][1] = w * ch1[p];
                acc[r][2] = w * ch2[p]; acc[r][3] = w * ch3[p];
                acc[r][4] = w;
            }
        }
    }
    #pragma unroll
    for (int r = 0; r < 4; ++r)
        pl_emit(cid[r], acc[r], sacc, smask, mycopy, exists, wcnt, wl);

    __syncthreads();

    // flush touched cells
    for (int i = threadIdx.x; i < CELLS; i += 512) {
        if (!((smask[i >> 5] >> (i & 31)) & 1u)) continue;
        int r = i & 3, q = i >> 2;
        int l0q = q % DQ; int t = q / DQ;
        int l1q = t % DQ; int l2q = t / DQ;
        int K0 = B0 + (l0q << 2) + r;
        int K1 = B1 + (l1q << 2) + r;
        int K2 = B2 + (l2q << 2) + r;
        int key = encK(K0 & 127, K1 & 127, K2 & 127);
        pl_claim(key, exists, wcnt, wl);
        float* L = mycopy + (size_t)key * 5;
        #pragma unroll
        for (int c = 0; c < 5; ++c) atomicAdd(L + c, sacc[i * 5 + c]);
    }
}

// ---------------------------------------------------------------- blur
// Single persistent kernel, BLURG blocks (all co-resident), 4 passes with
// atomic-counter grid barriers. Missing neighbors contribute 0 (matches the
// reference's failed hash lookup). Ping-pong latc(sum4)->A->B->A->B.
__device__ __forceinline__ void gbar(int* cnt, int nblk) {
    __syncthreads();
    __threadfence();
    if (threadIdx.x == 0) {
        __hip_atomic_fetch_add(cnt, 1, __ATOMIC_RELEASE, __HIP_MEMORY_SCOPE_AGENT);
        while (__hip_atomic_load(cnt, __ATOMIC_ACQUIRE, __HIP_MEMORY_SCOPE_AGENT) < nblk)
            __builtin_amdgcn_s_sleep(2);
    }
    __syncthreads();
    __threadfence();
}

__device__ __forceinline__ void blur_pass(const unsigned int* __restrict__ exists,
                                          const int* __restrict__ wl, int cnt5,
                                          const float* __restrict__ in,
                                          float* __restrict__ out,
                                          int d0, int d1, int d2, int first) {
    for (int i = blockIdx.x * 256 + threadIdx.x; i < cnt5; i += BLURG * 256) {
        int ci = i / 5, c = i - ci * 5;
        int didx = wl[ci];
        int r  = didx & 3;
        int K0 = (((didx >> 2)  & 31) << 2) | r;
        int K1 = (((didx >> 7)  & 31) << 2) | r;
        int K2 = (((didx >> 12) & 31) << 2) | r;
        size_t o = (size_t)didx * 5 + c;
        float ctr, n = 0.f;
        if (first)
            ctr = in[o] + in[LATF + o] + in[2 * LATF + o] + in[3 * LATF + o];
        else
            ctr = in[o];
        #pragma unroll
        for (int sgn = 0; sgn < 2; ++sgn) {
            int P0 = K0 + (sgn ? -d0 : d0);
            int P1 = K1 + (sgn ? -d1 : d1);
            int P2 = K2 + (sgn ? -d2 : d2);
            if (((unsigned)P0 < 128u) & ((unsigned)P1 < 128u) & ((unsigned)P2 < 128u)) {
                int nk = encK(P0, P1, P2);
                if (exists[nk]) {
                    size_t no = (size_t)nk * 5 + c;
                    if (first)
                        n += in[no] + in[LATF + no] + in[2 * LATF + no] + in[3 * LATF + no];
                    else
                        n += in[no];
                }
            }
        }
        out[o] = ctr + 0.5f * n;
    }
}

__global__ __launch_bounds__(256)
void pl_blur_fused(const unsigned int* __restrict__ exists,
                   const int* __restrict__ wl, const int* __restrict__ wcnt,
                   const float* __restrict__ latc, float* __restrict__ A,
                   float* __restrict__ B, int* __restrict__ bar) {
    int cnt5 = (*wcnt) * 5;
    blur_pass(exists, wl, cnt5, latc, A, -3, 1, 1, 1);
    gbar(bar + 0, BLURG);
    blur_pass(exists, wl, cnt5, A, B, 1, -3, 1, 0);
    gbar(bar + 1, BLURG);
    blur_pass(exists, wl, cnt5, B, A, 1, 1, -3, 0);
    gbar(bar + 2, BLURG);
    blur_pass(exists, wl, cnt5, A, B, 1, 1, 1, 0);
}

// ---------------------------------------------------------------- slice
__global__ __launch_bounds__(256)
void pl_slice(const float* __restrict__ vg, const float* __restrict__ sg,
              const float* __restrict__ lat, float* __restrict__ out) {
    int n = blockIdx.x * 256 + threadIdx.x;
    if (n >= NPTS) return;
    int z = n >> 14;
    int y = (n >> 7) & 127;
    int x = n & 127;
    int K[12]; float b[4];
    pl_geom(z, y, x, vg, sg, K, b);
    float a0 = 0.f, a1 = 0.f, a2 = 0.f, a3 = 0.f, a4 = 0.f;
    #pragma unroll
    for (int r = 0; r < 4; ++r) {
        float w = b[r];
        int key = encK(K[r * 3] & 127, K[r * 3 + 1] & 127, K[r * 3 + 2] & 127);
        const float* L = lat + (size_t)key * 5;
        a0 += w * L[0]; a1 += w * L[1]; a2 += w * L[2]; a3 += w * L[3]; a4 += w * L[4];
    }
    const float alpha = (float)(1.0 / 1.125);
    float norm = alpha * a4 + (float)2.220446049250313e-16;
    float invn = 1.0f / norm;
    out[n]            = (alpha * a0) * invn;
    out[NPTS + n]     = (alpha * a1) * invn;
    out[2 * NPTS + n] = (alpha * a2) * invn;
    out[3 * NPTS + n] = (alpha * a3) * invn;
}

// ---------------------------------------------------------------- launch
extern "C" void kernel_launch(void* const* d_in, const int* in_sizes, int n_in,
                              void* d_out, int out_size, void* d_ws, size_t ws_size,
                              hipStream_t stream) {
    const float* input = (const float*)d_in[0];   // (4,64,128,128)
    // d_in[1] = image: only its shape matters; unused.
    const float* vg = (const float*)d_in[2];
    const float* sg = (const float*)d_in[3];
    float* out = (float*)d_out;

    char* ws = (char*)d_ws;
    float* latc = (float*)ws;                              // 4 copies
    unsigned int* exists = (unsigned int*)(latc + (size_t)4 * LATF);
    int* wcnt = (int*)(exists + LATN);
    int* bar  = wcnt + 4;
    // ---- end of zeroed region ----
    int*   wl = (int*)(wcnt + 64);
    float* A  = (float*)(wl + LATN);
    float* B  = A + LATF;

    size_t zbytes = (size_t)4 * LATF * 4 + (size_t)LATN * 4 + 256;   // ~11 MB
    hipMemsetAsync(ws, 0, zbytes, stream);

    pl_splat<<<512, dim3(512), 0, stream>>>(input, vg, sg, latc, exists, wcnt, wl);
    pl_blur_fused<<<BLURG, dim3(256), 0, stream>>>(exists, wl, wcnt, latc, A, B, bar);
    pl_slice<<<NPTS / 256, dim3(256), 0, stream>>>(vg, sg, B, out);
}

// Round 12
// 153.985 us; speedup vs baseline: 1.3422x; 1.3422x over previous
//
#include <hip/hip_runtime.h>

// Permutohedral lattice filter, PD=3, VD=5 (4 channels + homogeneous 1)
// Dense-grid lattice addressing: keys (k0,k1,k2) all share residue mod 4 and
// (for the fixed feature scales coords/5) fit K0=k0+16, K1=k1+48, K2=k2+88,
// each in [0,128). Dense index = (K2>>2,K1>>2,K0>>2,K0&3) -> 2^17 cells.
//
// Splat: per-block DIRECT-MAPPED LDS box (no hash, no CAS) + register
// run-merging along x + lane-spread thread->x mapping + uniform dual-slot
// (current/pending) emission so LDS atomics issue at full wave occupancy.
// Blur: 4 small dispatches (dispatch boundaries beat device-scope barriers
// on MI355X — measured r5/r11). Slice: 4 px/thread with simplex-state reuse.

#define DD    64
#define HHH   128
#define WWW   128
#define NPTS  (DD * HHH * WWW)          // 1048576
#define LATN  (1 << 17)                 // dense lattice cells
#define LATF  (LATN * 5)                // floats per lattice buffer
#define NCPY  2                         // lat accumulation copies
#define DQ    7                         // box quads per axis
#define CELLS (DQ * DQ * DQ * 4)        // 1372
#define MASKW ((CELLS + 31) / 32)       // 43
#define NOID  0x7fffffff

__device__ __forceinline__ int encK(int K0, int K1, int K2) {
    return ((K2 >> 2) << 12) | ((K1 >> 2) << 7) | ((K0 >> 2) << 2) | (K0 & 3);
}

// Full per-point geometry: elevate, round (rintf; tie choice absorbed by the
// rank fixup basin), rank, barycentric. Outputs the 4 corner keys in offset
// K-space and weights. Returns a packed simplex-state id (exact: quantized
// rem0 + ranks) -- equal state => identical corner keys.
__device__ __forceinline__ int pl_geom(int z, int y, int x,
                                       const float* __restrict__ vg,
                                       const float* __restrict__ sg,
                                       int* Kout /*[4*3]*/, float* bout) {
    // features = [zz, yy, xx]; v_gamma[1] pairs with x, v_gamma[2] with y
    float f0 = vg[0] * (float)z / sg[0];
    float f1 = vg[2] * (float)y / sg[2];
    float f2 = vg[1] * (float)x / sg[1];

    const float m00 = (float)2.3094010767585034;   //  4/sqrt(3)
    const float m01 = (float)1.3333333333333333;   //  4/3
    const float m02 = (float)0.9428090415820634;   //  2*sqrt(2)/3
    const float m21 = (float)-2.6666666666666665;  // -2*(4/3)
    const float m32 = (float)-2.8284271247461903;  // -3*(2*sqrt(2)/3)

    float e[4];
    e[0] =  m00 * f0 + m01 * f1 + m02 * f2;
    e[1] = -m00 * f0 + m01 * f1 + m02 * f2;
    e[2] =  m21 * f1 + m02 * f2;
    e[3] =  m32 * f2;

    float rem0[4];
    int sumr = 0;
    #pragma unroll
    for (int i = 0; i < 4; ++i) {
        rem0[i] = rintf(e[i] * 0.25f) * 4.0f;
        sumr += (int)rem0[i];
    }
    sumr /= 4;   // exact: sum of multiples of 4

    float diff[4];
    #pragma unroll
    for (int i = 0; i < 4; ++i) diff[i] = e[i] - rem0[i];
    int rank[4] = {0, 0, 0, 0};
    #pragma unroll
    for (int i = 0; i < 4; ++i)
        #pragma unroll
        for (int j = i + 1; j < 4; ++j) {
            if (diff[i] < diff[j]) rank[i]++; else rank[j]++;
        }

    #pragma unroll
    for (int i = 0; i < 4; ++i) {
        rank[i] += sumr;
        if (rank[i] < 0)      { rank[i] += 4; rem0[i] += 4.0f; }
        else if (rank[i] > 3) { rank[i] -= 4; rem0[i] -= 4.0f; }
    }

    float b[5] = {0.f, 0.f, 0.f, 0.f, 0.f};
    #pragma unroll
    for (int i = 0; i < 4; ++i) {
        float t = (e[i] - rem0[i]) * 0.25f;
        b[3 - rank[i]] += t;
        b[4 - rank[i]] -= t;
    }
    b[0] += 1.0f + b[4];

    int k0 = (int)rem0[0] + 16, k1 = (int)rem0[1] + 48, k2 = (int)rem0[2] + 88;
    #pragma unroll
    for (int r = 0; r < 4; ++r) {
        int o0 = (rank[0] >= 4 - r) ? (r - 4) : r;
        int o1 = (rank[1] >= 4 - r) ? (r - 4) : r;
        int o2 = (rank[2] >= 4 - r) ? (r - 4) : r;
        Kout[r * 3 + 0] = k0 + o0;
        Kout[r * 3 + 1] = k1 + o1;
        Kout[r * 3 + 2] = k2 + o2;
        bout[r] = b[r];
    }
    // packed simplex state (k's are multiples of 4 plus fixed offsets)
    return ((k0 >> 2) + 32) | (((k1 >> 2) + 32) << 7) | (((k2 >> 2) + 32) << 14) |
           (rank[0] << 21) | (rank[1] << 23) | (rank[2] << 25);
}

// ---------------------------------------------------------------- splat
__device__ __forceinline__ void pl_claim(int key, unsigned int* __restrict__ exists,
                                         int* __restrict__ wcnt, int* __restrict__ wl) {
    if (atomicExch(&exists[key], 1u) == 0u) {
        int p = atomicAdd(wcnt, 1);
        wl[p] = key;
    }
}

// id >= 0 : box cell index.  id < 0 : ~id = dense lattice key (escape).
__device__ __forceinline__ int make_id(const int* K, int B0, int B1, int B2) {
    int l0 = K[0] - B0, l1 = K[1] - B1, l2 = K[2] - B2;
    if (((unsigned)l0 < 4u * DQ) & ((unsigned)l1 < 4u * DQ) & ((unsigned)l2 < 4u * DQ))
        return ((((l2 >> 2) * DQ) + (l1 >> 2)) * DQ + (l0 >> 2)) * 4 + (l0 & 3);
    return ~encK(K[0] & 127, K[1] & 127, K[2] & 127);
}

__device__ __forceinline__ void pl_emit(int id, const float* a,
                                        float* sacc, unsigned int* smask,
                                        float* __restrict__ mycopy,
                                        unsigned int* __restrict__ exists,
                                        int* __restrict__ wcnt, int* __restrict__ wl) {
    if (id >= 0) {
        #pragma unroll
        for (int c = 0; c < 5; ++c) atomicAdd(&sacc[id * 5 + c], a[c]);
        atomicOr(&smask[id >> 5], 1u << (id & 31));
    } else {                              // out-of-box escape (rare)
        int key = ~id;
        float* L = mycopy + (size_t)key * 5;
        #pragma unroll
        for (int c = 0; c < 5; ++c) atomicAdd(L + c, a[c]);
        pl_claim(key, exists, wcnt, wl);
    }
}

// Block = 256 threads covering a 32x8x4 (x,y,z) tile, 4 consecutive x px per
// thread with register run-merging; thread->x slot spread so adjacent lanes
// are 8 px apart. On id change the old accumulator moves to a register
// "pending" slot; ALL emits happen uniformly after the px loop (4 current +
// 4 pending), so LDS atomics issue with full-wave masks. A second id change
// within the 4-px window (rare: run ~6.7 px) emits the pending immediately.
__global__ __launch_bounds__(256, 4)
void pl_splat(const float* __restrict__ vals, const float* __restrict__ vg,
              const float* __restrict__ sg, float* __restrict__ latc,
              unsigned int* __restrict__ exists,
              int* __restrict__ wcnt, int* __restrict__ wl) {
    __shared__ float4 sacc4[CELLS * 5 / 4 + 1];   // 27.4 KB
    __shared__ unsigned int smask[MASKW];
    float* sacc = (float*)sacc4;
    for (int i = threadIdx.x; i < CELLS * 5 / 4 + 1; i += 256)
        sacc4[i] = make_float4(0.f, 0.f, 0.f, 0.f);
    if (threadIdx.x < MASKW) smask[threadIdx.x] = 0u;
    __syncthreads();

    // tile decode: grid = 4(x) * 16(y) * 16(z) = 1024 blocks
    int bt = blockIdx.x;
    int tx = (bt & 3) << 5;
    int ty = ((bt >> 2) & 15) << 3;
    int tz = (bt >> 6) << 2;

    // per-block box base (uniform): analytic min corner of the key range.
    // K - e in [-7, 6]  =>  base = floor(emin + OFF - 7) & ~3.
    float s0 = vg[0] / sg[0], s1 = vg[2] / sg[2], s2 = vg[1] / sg[1];
    const float m00 = 2.30940104f, m01 = 1.33333325f, m02 = 0.942809045f,
                m21 = -2.66666651f;
    float A0z = m00 * s0, A0y = m01 * s1, A0x = m02 * s2;
    float A1z = -A0z,     A1y = A0y,      A1x = A0x;
    float A2y = m21 * s1, A2x = A0x;
    float e0o = A0z * tz + A0y * ty + A0x * tx;
    float e1o = A1z * tz + A1y * ty + A1x * tx;
    float e2o = A2y * ty + A2x * tx;
    float e0m = e0o + fminf(0.f, A0z) * 3 + fminf(0.f, A0y) * 7 + fminf(0.f, A0x) * 31;
    float e1m = e1o + fminf(0.f, A1z) * 3 + fminf(0.f, A1y) * 7 + fminf(0.f, A1x) * 31;
    float e2m = e2o + fminf(0.f, A2y) * 7 + fminf(0.f, A2x) * 31;
    int B0 = ((int)floorf(e0m + 16.f - 7.f)) & ~3;
    int B1 = ((int)floorf(e1m + 48.f - 7.f)) & ~3;
    int B2 = ((int)floorf(e2m + 88.f - 7.f)) & ~3;

    // thread -> x slot, spread so adjacent lanes are 8 px apart
    int xs = threadIdx.x & 7;
    int xsl = ((xs & 3) << 1) | (xs >> 2);   // 0,2,4,6,1,3,5,7
    int x0 = tx + (xsl << 2);
    int y  = ty + ((threadIdx.x >> 3) & 7);
    int z  = tz + (threadIdx.x >> 6);
    int n0 = (z << 14) + (y << 7) + x0;

    float4 q0 = *(const float4*)(vals + n0);
    float4 q1 = *(const float4*)(vals + NPTS + n0);
    float4 q2 = *(const float4*)(vals + 2 * NPTS + n0);
    float4 q3 = *(const float4*)(vals + 3 * NPTS + n0);
    float ch0[4] = {q0.x, q0.y, q0.z, q0.w};
    float ch1[4] = {q1.x, q1.y, q1.z, q1.w};
    float ch2[4] = {q2.x, q2.y, q2.z, q2.w};
    float ch3[4] = {q3.x, q3.y, q3.z, q3.w};

    float* mycopy = latc + (size_t)(blockIdx.x & (NCPY - 1)) * LATF;

    int cid[4], pid[4];
    float cacc[4][5], pacc[4][5];
    {
        int K[12]; float b[4];
        pl_geom(z, y, x0, vg, sg, K, b);
        #pragma unroll
        for (int r = 0; r < 4; ++r) {
            cid[r] = make_id(K + r * 3, B0, B1, B2);
            pid[r] = NOID;
            float w = b[r];
            cacc[r][0] = w * ch0[0]; cacc[r][1] = w * ch1[0];
            cacc[r][2] = w * ch2[0]; cacc[r][3] = w * ch3[0];
            cacc[r][4] = w;
        }
    }
    #pragma unroll
    for (int p = 1; p < 4; ++p) {
        int K[12]; float b[4];
        pl_geom(z, y, x0 + p, vg, sg, K, b);
        #pragma unroll
        for (int r = 0; r < 4; ++r) {
            int id = make_id(K + r * 3, B0, B1, B2);
            float w = b[r];
            if (id == cid[r]) {   // register run-merge (hit rate ~85%)
                cacc[r][0] += w * ch0[p]; cacc[r][1] += w * ch1[p];
                cacc[r][2] += w * ch2[p]; cacc[r][3] += w * ch3[p];
                cacc[r][4] += w;
            } else {
                if (pid[r] != NOID)    // rare 2nd change: emit old pending
                    pl_emit(pid[r], pacc[r], sacc, smask, mycopy, exists, wcnt, wl);
                pid[r] = cid[r];
                #pragma unroll
                for (int c = 0; c < 5; ++c) pacc[r][c] = cacc[r][c];
                cid[r] = id;
                cacc[r][0] = w * ch0[p]; cacc[r][1] = w * ch1[p];
                cacc[r][2] = w * ch2[p]; cacc[r][3] = w * ch3[p];
                cacc[r][4] = w;
            }
        }
    }
    // uniform emission
    #pragma unroll
    for (int r = 0; r < 4; ++r) {
        if (pid[r] != NOID)
            pl_emit(pid[r], pacc[r], sacc, smask, mycopy, exists, wcnt, wl);
        pl_emit(cid[r], cacc[r], sacc, smask, mycopy, exists, wcnt, wl);
    }
    __syncthreads();

    // flush touched cells
    for (int i = threadIdx.x; i < CELLS; i += 256) {
        if (!((smask[i >> 5] >> (i & 31)) & 1u)) continue;
        int r = i & 3, q = i >> 2;
        int l0q = q % DQ; int t = q / DQ;
        int l1q = t % DQ; int l2q = t / DQ;
        int K0 = B0 + (l0q << 2) + r;
        int K1 = B1 + (l1q << 2) + r;
        int K2 = B2 + (l2q << 2) + r;
        int key = encK(K0 & 127, K1 & 127, K2 & 127);
        pl_claim(key, exists, wcnt, wl);
        float* L = mycopy + (size_t)key * 5;
        #pragma unroll
        for (int c = 0; c < 5; ++c) atomicAdd(L + c, sacc[i * 5 + c]);
    }
}

// ---------------------------------------------------------------- blur
// One thread per (active cell, channel); 3 gated loads + 1 store. first!=0:
// input is the NCPY-copy splat buffer, summed on the fly. Missing neighbors
// contribute 0 (matches the reference's failed hash lookup).
__global__ __launch_bounds__(256)
void pl_blur(const unsigned int* __restrict__ exists,
             const int* __restrict__ wl, const int* __restrict__ wcnt,
             const float* __restrict__ in, float* __restrict__ out,
             int d0, int d1, int d2, int first) {
    int total = (*wcnt) * 5;
    for (int i = blockIdx.x * 256 + threadIdx.x; i < total; i += 256 * 256) {
        int ci = i / 5, c = i - ci * 5;
        int didx = wl[ci];
        int r  = didx & 3;
        int K0 = (((didx >> 2)  & 31) << 2) | r;
        int K1 = (((didx >> 7)  & 31) << 2) | r;
        int K2 = (((didx >> 12) & 31) << 2) | r;
        size_t o = (size_t)didx * 5 + c;
        float ctr, n = 0.f;
        if (first) ctr = in[o] + in[LATF + o];
        else       ctr = in[o];
        #pragma unroll
        for (int sgn = 0; sgn < 2; ++sgn) {
            int P0 = K0 + (sgn ? -d0 : d0);
            int P1 = K1 + (sgn ? -d1 : d1);
            int P2 = K2 + (sgn ? -d2 : d2);
            if (((unsigned)P0 < 128u) & ((unsigned)P1 < 128u) & ((unsigned)P2 < 128u)) {
                int nk = encK(P0, P1, P2);
                if (exists[nk]) {
                    size_t no = (size_t)nk * 5 + c;
                    if (first) n += in[no] + in[LATF + no];
                    else       n += in[no];
                }
            }
        }
        out[o] = ctr + 0.5f * n;
    }
}

// ---------------------------------------------------------------- slice
// 4 px per thread: lattice values are re-gathered only when the simplex
// state changes (run ~6.7 px); float4 output stores.
__global__ __launch_bounds__(256)
void pl_slice(const float* __restrict__ vg, const float* __restrict__ sg,
              const float* __restrict__ lat, float* __restrict__ out) {
    int t = blockIdx.x * 256 + threadIdx.x;      // 0 .. NPTS/4-1
    int n0 = t << 2;
    int z = n0 >> 14;
    int y = (n0 >> 7) & 127;
    int x0 = n0 & 127;
    float r0[4], r1[4], r2[4], r3[4];
    int Sprev = -1;
    float Lv[4][5];
    #pragma unroll
    for (int p = 0; p < 4; ++p) {
        int K[12]; float b[4];
        int S = pl_geom(z, y, x0 + p, vg, sg, K, b);
        if (S != Sprev) {
            Sprev = S;
            #pragma unroll
            for (int r = 0; r < 4; ++r) {
                int key = encK(K[r * 3] & 127, K[r * 3 + 1] & 127, K[r * 3 + 2] & 127);
                const float* L = lat + (size_t)key * 5;
                #pragma unroll
                for (int c = 0; c < 5; ++c) Lv[r][c] = L[c];
            }
        }
        float a0 = 0.f, a1 = 0.f, a2 = 0.f, a3 = 0.f, a4 = 0.f;
        #pragma unroll
        for (int r = 0; r < 4; ++r) {
            float w = b[r];
            a0 += w * Lv[r][0]; a1 += w * Lv[r][1]; a2 += w * Lv[r][2];
            a3 += w * Lv[r][3]; a4 += w * Lv[r][4];
        }
        const float alpha = (float)(1.0 / 1.125);
        float invn = 1.0f / (alpha * a4 + (float)2.220446049250313e-16);
        r0[p] = alpha * a0 * invn;
        r1[p] = alpha * a1 * invn;
        r2[p] = alpha * a2 * invn;
        r3[p] = alpha * a3 * invn;
    }
    *(float4*)(out + n0)            = make_float4(r0[0], r0[1], r0[2], r0[3]);
    *(float4*)(out + NPTS + n0)     = make_float4(r1[0], r1[1], r1[2], r1[3]);
    *(float4*)(out + 2 * NPTS + n0) = make_float4(r2[0], r2[1], r2[2], r2[3]);
    *(float4*)(out + 3 * NPTS + n0) = make_float4(r3[0], r3[1], r3[2], r3[3]);
}

// ---------------------------------------------------------------- launch
extern "C" void kernel_launch(void* const* d_in, const int* in_sizes, int n_in,
                              void* d_out, int out_size, void* d_ws, size_t ws_size,
                              hipStream_t stream) {
    const float* input = (const float*)d_in[0];   // (4,64,128,128)
    // d_in[1] = image: only its shape matters; unused.
    const float* vg = (const float*)d_in[2];
    const float* sg = (const float*)d_in[3];
    float* out = (float*)d_out;

    char* ws = (char*)d_ws;
    float* latc = (float*)ws;                              // NCPY copies
    unsigned int* exists = (unsigned int*)(latc + (size_t)NCPY * LATF);
    int* wcnt = (int*)(exists + LATN);
    // ---- end of zeroed region ----
    int*   wl = (int*)(wcnt + 64);
    float* A  = (float*)(wl + LATN);
    float* B  = A + LATF;

    size_t zbytes = (size_t)NCPY * LATF * 4 + (size_t)LATN * 4 + 256;   // ~5.8 MB
    hipMemsetAsync(ws, 0, zbytes, stream);

    pl_splat<<<1024, dim3(256), 0, stream>>>(input, vg, sg, latc, exists, wcnt, wl);

    // blur passes: j=0..2 -> o = ones with o[j] = -3; j=3 -> o = ones
    // ping-pong: latc(sum2) -> A -> B -> A -> B; slice reads B
    pl_blur<<<256, dim3(256), 0, stream>>>(exists, wl, wcnt, latc, A, -3, 1, 1, 1);
    pl_blur<<<256, dim3(256), 0, stream>>>(exists, wl, wcnt, A, B, 1, -3, 1, 0);
    pl_blur<<<256, dim3(256), 0, stream>>>(exists, wl, wcnt, B, A, 1, 1, -3, 0);
    pl_blur<<<256, dim3(256), 0, stream>>>(exists, wl, wcnt, A, B, 1, 1, 1, 0);

    pl_slice<<<NPTS / 4 / 256, dim3(256), 0, stream>>>(vg, sg, B, out);
}